// Round 17
// baseline (309.603 us; speedup 1.0000x reference)
//
#include <hip/hip_runtime.h>

#define N_NODES 50000
#define E_EDGES 400000
#define DIM     512
#define NRSU    1000
#define NVEH    (N_NODES - NRSU)
#define NB_SCAN 196           // ceil(50000/256)

typedef __attribute__((ext_vector_type(8))) __bf16 bf16x8;
typedef __attribute__((ext_vector_type(4))) float  f32x4;
typedef __attribute__((ext_vector_type(8))) unsigned short ush8v;
typedef __attribute__((ext_vector_type(4))) unsigned short ush4v;

// ---------- bf16 helpers (RNE) ----------
__device__ __forceinline__ unsigned short f2bf_rne(float x) {
    unsigned u = __float_as_uint(x);
    unsigned r = u + 0x7fff + ((u >> 16) & 1);
    return (unsigned short)(r >> 16);
}
// unpack 8 packed bf16 (uint4) -> 8 floats
__device__ __forceinline__ void cvt8(uint4 v, float* f) {
    f[0] = __uint_as_float(v.x << 16); f[1] = __uint_as_float(v.x & 0xffff0000u);
    f[2] = __uint_as_float(v.y << 16); f[3] = __uint_as_float(v.y & 0xffff0000u);
    f[4] = __uint_as_float(v.z << 16); f[5] = __uint_as_float(v.z & 0xffff0000u);
    f[6] = __uint_as_float(v.w << 16); f[7] = __uint_as_float(v.w & 0xffff0000u);
}
// unpack 4 packed bf16 (uint2) -> 4 floats
__device__ __forceinline__ void cvt4(uint2 v, float* f) {
    f[0] = __uint_as_float(v.x << 16); f[1] = __uint_as_float(v.x & 0xffff0000u);
    f[2] = __uint_as_float(v.y << 16); f[3] = __uint_as_float(v.y & 0xffff0000u);
}

// ---------- async global->LDS (16B per lane) ----------
typedef __attribute__((address_space(1))) const unsigned char ga_u8;
typedef __attribute__((address_space(3))) unsigned char la_u8;
__device__ __forceinline__ void gload16(const void* g, void* l) {
    __builtin_amdgcn_global_load_lds((ga_u8*)g, (la_u8*)l, 16, 0, 0);
}

// ---------------- fused prep: zero(cnt) | segbounds | W^T | x->bf16 ----------------
#define PREP_B0 196
#define PREP_B1 (PREP_B0 + 192)
#define PREP_B2 (PREP_B1 + 2 * DIM)
__global__ __launch_bounds__(256) void k_prep(int* __restrict__ cnt,
                                              const int* __restrict__ batch,
                                              int* __restrict__ seg,
                                              const float* __restrict__ W1,
                                              const float* __restrict__ W2,
                                              unsigned short* __restrict__ W1T,
                                              unsigned short* __restrict__ W2T,
                                              const float* __restrict__ x,
                                              unsigned short* __restrict__ xb) {
    int b = blockIdx.x;
    if (b < PREP_B0) {
        int i = b * 256 + threadIdx.x;
        if (i < N_NODES) cnt[i] = 0;
    } else if (b < PREP_B1) {
        int v = (b - PREP_B0) * 256 + threadIdx.x;
        if (v >= NVEH) return;
        int bb = batch[NRSU + v];
        if (v == 0) {
            for (int s = 0; s <= bb; ++s) seg[s] = 0;
        } else {
            int bp = batch[NRSU + v - 1];
            for (int s = bp + 1; s <= bb; ++s) seg[s] = v;
        }
        if (v == NVEH - 1) {
            for (int s = bb + 1; s <= NRSU; ++s) seg[s] = NVEH;
        }
    } else if (b < PREP_B2) {
        int idx = b - PREP_B1;
        const float* W = (idx >= DIM) ? W2 : W1;
        unsigned short* WT = (idx >= DIM) ? W2T : W1T;
        int n = idx & (DIM - 1);
        for (int k = threadIdx.x; k < DIM; k += 256)
            WT[(size_t)n * DIM + k] = f2bf_rne(W[(size_t)k * DIM + n]);
    } else {
        size_t i = ((size_t)(b - PREP_B2) * 256 + threadIdx.x) * 8;
        float4 a = *reinterpret_cast<const float4*>(x + i);
        float4 c = *reinterpret_cast<const float4*>(x + i + 4);
        ush8v o;
        o[0] = f2bf_rne(a.x); o[1] = f2bf_rne(a.y); o[2] = f2bf_rne(a.z); o[3] = f2bf_rne(a.w);
        o[4] = f2bf_rne(c.x); o[5] = f2bf_rne(c.y); o[6] = f2bf_rne(c.z); o[7] = f2bf_rne(c.w);
        *reinterpret_cast<ush8v*>(xb + i) = o;
    }
}

// ---------------- in-degree count ----------------
__global__ void k_count(const int* __restrict__ dst, int* __restrict__ cnt) {
    int e = blockIdx.x * 256 + threadIdx.x;
    if (e < E_EDGES) atomicAdd(&cnt[dst[e]], 1);
}

// ---------------- block-wise exclusive scan ----------------
__global__ __launch_bounds__(256) void k_scan1(const int* __restrict__ cnt,
                                               int* __restrict__ rowptr,
                                               int* __restrict__ bsum) {
    __shared__ int sh[256];
    int tid = threadIdx.x;
    int i = blockIdx.x * 256 + tid;
    int v = (i < N_NODES) ? cnt[i] : 0;
    sh[tid] = v;
    __syncthreads();
    #pragma unroll
    for (int off = 1; off < 256; off <<= 1) {
        int t = (tid >= off) ? sh[tid - off] : 0;
        __syncthreads();
        sh[tid] += t;
        __syncthreads();
    }
    if (i < N_NODES) rowptr[i] = sh[tid] - v;
    if (tid == 255) bsum[blockIdx.x] = sh[255];
}

__global__ __launch_bounds__(256) void k_scan2(int* __restrict__ bsum) {
    __shared__ int sh[256];
    int tid = threadIdx.x;
    int v = (tid < NB_SCAN) ? bsum[tid] : 0;
    sh[tid] = v;
    __syncthreads();
    #pragma unroll
    for (int off = 1; off < 256; off <<= 1) {
        int t = (tid >= off) ? sh[tid - off] : 0;
        __syncthreads();
        sh[tid] += t;
        __syncthreads();
    }
    if (tid < NB_SCAN) bsum[tid] = sh[tid] - v;
}

// scan finalize + dinv + zero fill counters (merged)
__global__ void k_scan3(int* __restrict__ rowptr, const int* __restrict__ bsum,
                        int* __restrict__ cntfill, float* __restrict__ dinv) {
    int i = blockIdx.x * 256 + threadIdx.x;
    if (i < N_NODES) {
        rowptr[i] += bsum[blockIdx.x];
        int c = cntfill[i];
        dinv[i] = rsqrtf((float)c + 1.0f);   // self-loop
        cntfill[i] = 0;                      // becomes fill counter
    }
    if (i == 0) rowptr[N_NODES] = E_EDGES;
}

// ---------------- CSR fill (+ precomputed edge weights) ----------------
__global__ void k_fill(const int* __restrict__ ei, const int* __restrict__ rowptr,
                       int* __restrict__ fill, int* __restrict__ col,
                       const float* __restrict__ dinv, float* __restrict__ wnorm) {
    int e = blockIdx.x * 256 + threadIdx.x;
    if (e >= E_EDGES) return;
    int s = ei[e];
    int d = ei[E_EDGES + e];
    int p = atomicAdd(&fill[d], 1);
    int idx = rowptr[d] + p;
    col[idx] = s;
    wnorm[idx] = dinv[s] * dinv[d];
}

// ---------------- bf16 MFMA GEMM: 4-deep pipelined LDS, counted vmcnt ----------------
// 4 buffers; per iter: wait(tile t) -> s_barrier -> issue stage(t+3) -> compute(t).
// Issuing AFTER the barrier makes the buf[(t-1)&3] overwrite safe (all waves done
// reading it). vmcnt(8) leaves the 2 newest tiles in flight (T4: never drain to 0).
template<int MODE>
__global__ __launch_bounds__(256) void k_gemm_mfma(const unsigned short* __restrict__ Ab,
                                                   const unsigned short* __restrict__ BT,
                                                   float* __restrict__ C,
                                                   unsigned short* __restrict__ Cb, int M,
                                                   const float* __restrict__ bias,
                                                   const float* __restrict__ bscale) {
    const int BM = 128, BN = 128, BK = 32, NT = DIM / BK;   // NT = 16
    __shared__ unsigned short sA[4][BM * BK];   // 32 KB
    __shared__ unsigned short sB[4][BN * BK];   // 32 KB

    int tid = threadIdx.x;
    int wv = tid >> 6;
    int ln = tid & 63;

    int wgid;
    if (MODE == 2) {
        const int q = 195, r = 4;      // nwg = 1564 = 8*195 + 4
        int id = blockIdx.x;
        int xcd = id & 7, idx = id >> 3;
        wgid = (xcd < r ? xcd * (q + 1) : r * (q + 1) + (xcd - r) * q) + idx;
    } else {
        wgid = blockIdx.x;
    }
    int col0 = (wgid & 3) * BN;
    int row0 = (wgid >> 2) * BM;

    int wr = wv >> 1, wc = wv & 1;
    int fr = ln & 15;
    int ks16 = ln >> 4;

    int sidx0 = tid, sidx1 = 256 + tid;
    int r0 = sidx0 >> 2, s0 = sidx0 & 3;
    int r1 = sidx1 >> 2, s1 = sidx1 & 3;
    int c0 = ((s0 ^ ((r0 >> 1) & 3)) << 3);
    int c1 = ((s1 ^ ((r1 >> 1) & 3)) << 3);
    int ar0 = row0 + r0; if (ar0 > M - 1) ar0 = M - 1;
    int ar1 = row0 + r1; if (ar1 > M - 1) ar1 = M - 1;
    const unsigned short* ga0 = Ab + (size_t)ar0 * DIM + c0;
    const unsigned short* ga1 = Ab + (size_t)ar1 * DIM + c1;
    const unsigned short* gb0 = BT + (size_t)(col0 + r0) * DIM + c0;
    const unsigned short* gb1 = BT + (size_t)(col0 + r1) * DIM + c1;
    int lb0 = wv * 1024;
    int lb1 = 4096 + wv * 1024;

    f32x4 zero = {0.f, 0.f, 0.f, 0.f};
    f32x4 acc[4][4];
    #pragma unroll
    for (int m = 0; m < 4; ++m)
        #pragma unroll
        for (int n = 0; n < 4; ++n) acc[m][n] = zero;

    // prologue: stage tiles 0,1,2 (12 loads outstanding per thread)
    #pragma unroll
    for (int t = 0; t < 3; ++t) {
        int k0 = t * BK;
        gload16(ga0 + k0, (char*)sA[t] + lb0);
        gload16(ga1 + k0, (char*)sA[t] + lb1);
        gload16(gb0 + k0, (char*)sB[t] + lb0);
        gload16(gb1 + k0, (char*)sB[t] + lb1);
    }

    #pragma unroll
    for (int t = 0; t < NT; ++t) {
        // 1. wait until tile t's loads have landed (leave newer tiles in flight)
        if (t < NT - 2)      asm volatile("s_waitcnt vmcnt(8)" ::: "memory");
        else if (t == NT - 2) asm volatile("s_waitcnt vmcnt(4)" ::: "memory");
        else                  asm volatile("s_waitcnt vmcnt(0)" ::: "memory");
        // 2. barrier: all waves' tile-t loads landed; all done reading buf[(t+3)&3]
        __builtin_amdgcn_s_barrier();
        // 3. issue stage(t+3) into buf[(t+3)&3]
        if (t + 3 < NT) {
            int k0n = (t + 3) * BK;
            int bn = (t + 3) & 3;
            gload16(ga0 + k0n, (char*)sA[bn] + lb0);
            gload16(ga1 + k0n, (char*)sA[bn] + lb1);
            gload16(gb0 + k0n, (char*)sB[bn] + lb0);
            gload16(gb1 + k0n, (char*)sB[bn] + lb1);
        }
        // 4. compute tile t
        int cur = t & 3;
        bf16x8 a[4], b[4];
        #pragma unroll
        for (int m = 0; m < 4; ++m) {
            int r = wr * 64 + m * 16 + fr;
            int e = r * BK + ((ks16 ^ ((r >> 1) & 3)) << 3);
            a[m] = *reinterpret_cast<const bf16x8*>(&sA[cur][e]);
        }
        #pragma unroll
        for (int n = 0; n < 4; ++n) {
            int r = wc * 64 + n * 16 + fr;
            int e = r * BK + ((ks16 ^ ((r >> 1) & 3)) << 3);
            b[n] = *reinterpret_cast<const bf16x8*>(&sB[cur][e]);
        }
        #pragma unroll
        for (int m = 0; m < 4; ++m)
            #pragma unroll
            for (int n = 0; n < 4; ++n)
                acc[m][n] = __builtin_amdgcn_mfma_f32_16x16x32_bf16(a[m], b[n], acc[m][n], 0, 0, 0);
    }

    int rbase = row0 + wr * 64 + (ln >> 4) * 4;
    int cbase = col0 + wc * 64 + (ln & 15);
    #pragma unroll
    for (int m = 0; m < 4; ++m)
        #pragma unroll
        for (int r4 = 0; r4 < 4; ++r4) {
            int row = rbase + m * 16 + r4;
            if (row < M) {
                if (MODE == 2) {
                    #pragma unroll
                    for (int n = 0; n < 4; ++n) {
                        int cc = cbase + n * 16;
                        Cb[(size_t)row * DIM + cc] =
                            f2bf_rne(fmaxf(acc[m][n][r4] + bias[cc], 0.f));
                    }
                } else {
                    float bs = bscale[row];
                    float* dst = (row < NRSU) ? (C + (size_t)row * 1024)
                                              : (C + (size_t)(row - NRSU) * 1024 + 512);
                    #pragma unroll
                    for (int n = 0; n < 4; ++n) {
                        int cc = cbase + n * 16;
                        dst[cc] = acc[m][n][r4] + bias[cc] * bs;
                    }
                }
            }
        }
}

// ---------------- col-split CSR gather on bf16 rows -> bf16 plane ----------------
__global__ __launch_bounds__(256) void k_gather_bf(const int* __restrict__ rowptr,
                                                   const int* __restrict__ col,
                                                   const float* __restrict__ wnorm,
                                                   const float* __restrict__ dinv,
                                                   const unsigned short* __restrict__ pre,
                                                   unsigned short* __restrict__ ob,
                                                   int coff) {
    int node = blockIdx.x * 4 + (threadIdx.x >> 6);
    if (node >= N_NODES) return;
    int lane = threadIdx.x & 63;
    int c = coff + lane * 4;

    float di = dinv[node];
    float w0 = di * di;
    float s[4], t[4];
    {
        uint2 sv = *reinterpret_cast<const uint2*>(pre + (size_t)node * DIM + c);
        float fa[4]; cvt4(sv, fa);
        #pragma unroll
        for (int i = 0; i < 4; ++i) { s[i] = w0 * fa[i]; t[i] = 0.f; }
    }

    int beg = rowptr[node], end = rowptr[node + 1];
    int deg = end - beg;
    for (int j0 = 0; j0 < deg; j0 += 64) {
        int j = j0 + lane;
        int cj = 0; float wj = 0.f;
        if (j < deg) { cj = col[beg + j]; wj = wnorm[beg + j]; }
        int lim = deg - j0; if (lim > 64) lim = 64;
        for (int jj = 0; jj < lim; jj += 8) {
            int sidx[8]; float sw[8];
            #pragma unroll
            for (int q = 0; q < 8; ++q) {
                sidx[q] = __shfl(cj, jj + q);
                sw[q]   = __shfl(wj, jj + q);
            }
            uint2 v[8];
            #pragma unroll
            for (int q = 0; q < 8; ++q)
                v[q] = *reinterpret_cast<const uint2*>(pre + (size_t)sidx[q] * DIM + c);
            #pragma unroll
            for (int q = 0; q < 8; ++q) {
                float f[4]; cvt4(v[q], f);
                if ((q & 1) == 0) {
                    #pragma unroll
                    for (int i = 0; i < 4; ++i) s[i] = fmaf(sw[q], f[i], s[i]);
                } else {
                    #pragma unroll
                    for (int i = 0; i < 4; ++i) t[i] = fmaf(sw[q], f[i], t[i]);
                }
            }
        }
    }
    ush4v h;
    #pragma unroll
    for (int i = 0; i < 4; ++i) h[i] = f2bf_rne(s[i] + t[i]);
    *reinterpret_cast<ush4v*>(ob + (size_t)node * DIM + c) = h;
}

// ---------------- pool from bf16 A2 -> single SPb plane ----------------
__global__ __launch_bounds__(64) void k_pool_sp(const unsigned short* __restrict__ A2b,
                                                const int* __restrict__ seg,
                                                unsigned short* __restrict__ SPb,
                                                float* __restrict__ bscale) {
    int s = blockIdx.x;
    int c = threadIdx.x * 8;
    {
        uint4 v = *reinterpret_cast<const uint4*>(A2b + (size_t)s * DIM + c);
        *reinterpret_cast<uint4*>(SPb + (size_t)s * DIM + c) = v;
    }
    int beg = seg[s], end = seg[s + 1];
    float acc[8] = {0.f, 0.f, 0.f, 0.f, 0.f, 0.f, 0.f, 0.f};
    for (int v = beg; v < end; ++v) {
        uint4 t = *reinterpret_cast<const uint4*>(A2b + (size_t)(NRSU + v) * DIM + c);
        float f[8]; cvt8(t, f);
        #pragma unroll
        for (int i = 0; i < 8; ++i) acc[i] += f[i];
    }
    float inv = 1.0f / fmaxf((float)(end - beg), 1.0f);
    ush8v h;
    #pragma unroll
    for (int i = 0; i < 8; ++i) h[i] = f2bf_rne(acc[i] * inv);
    *reinterpret_cast<ush8v*>(SPb + (size_t)(NRSU + s) * DIM + c) = h;
    if (threadIdx.x == 0) {
        bscale[s] = 1.0f;
        bscale[NRSU + s] = (end > beg) ? 1.0f : 0.0f;
    }
}

extern "C" void kernel_launch(void* const* d_in, const int* in_sizes, int n_in,
                              void* d_out, int out_size, void* d_ws, size_t ws_size,
                              hipStream_t stream) {
    const float* x     = (const float*)d_in[0];
    const int*   ei    = (const int*)d_in[1];
    const int*   batch = (const int*)d_in[2];
    const float* W1    = (const float*)d_in[3];
    const float* b1    = (const float*)d_in[4];
    const float* W2    = (const float*)d_in[5];
    const float* b2    = (const float*)d_in[6];
    float* out = (float*)d_out;

    char* ws = (char*)d_ws;
    const size_t HALF = (size_t)N_NODES * DIM * 2;
    unsigned short* Axb = (unsigned short*)(ws);
    unsigned short* A2b = (unsigned short*)(ws);
    unsigned short* h1b = (unsigned short*)(ws + 2 * HALF);
    unsigned short* xb  = (unsigned short*)(ws + 3 * HALF);
    char* p = ws + 4 * HALF;
    float* dinv    = (float*)p;                p += (size_t)N_NODES * 4;
    int*   cnt     = (int*)p;                  p += (size_t)N_NODES * 4;
    int*   rowptr  = (int*)p;                  p += (size_t)(N_NODES + 4) * 4;
    int*   col     = (int*)p;                  p += (size_t)E_EDGES * 4;
    float* wnorm   = (float*)p;                p += (size_t)E_EDGES * 4;
    int*   bsum    = (int*)p;                  p += 1024;
    int*   seg     = (int*)p;                  p += (size_t)(NRSU + 8) * 4;
    unsigned short* SPb = (unsigned short*)p;  p += (size_t)2 * NRSU * DIM * 2;
    float* bscale  = (float*)p;                p += (size_t)2 * NRSU * 4;
    unsigned short* W1T = (unsigned short*)p;  p += (size_t)DIM * DIM * 2;
    unsigned short* W2T = (unsigned short*)p;  p += (size_t)DIM * DIM * 2;

    dim3 blk(256);
    const int gN = (N_NODES + 255) / 256;
    const int gE = (E_EDGES + 255) / 256;

    const int PREP_NB = PREP_B2 + (int)((size_t)N_NODES * DIM / 8 / 256);
    k_prep  <<<PREP_NB, blk, 0, stream>>>(cnt, batch, seg, W1, W2, W1T, W2T, x, xb);
    k_count <<<gE, blk, 0, stream>>>(ei + E_EDGES, cnt);
    k_scan1 <<<gN, blk, 0, stream>>>(cnt, rowptr, bsum);
    k_scan2 <<<1,  blk, 0, stream>>>(bsum);
    k_scan3 <<<gN, blk, 0, stream>>>(rowptr, bsum, cnt, dinv);
    k_fill  <<<gE, blk, 0, stream>>>(ei, rowptr, cnt, col, dinv, wnorm);

    const int GG = (N_NODES + 3) / 4;

    // ---- layer 1 ----
    k_gather_bf<<<GG, blk, 0, stream>>>(rowptr, col, wnorm, dinv, xb, Axb, 0);
    k_gather_bf<<<GG, blk, 0, stream>>>(rowptr, col, wnorm, dinv, xb, Axb, 256);
    const int NWG1 = ((N_NODES + 127) / 128) * 4;   // 1564
    k_gemm_mfma<2><<<NWG1, blk, 0, stream>>>(Axb, W1T, nullptr, h1b, N_NODES, b1, nullptr);

    // ---- layer 2 ----
    k_gather_bf<<<GG, blk, 0, stream>>>(rowptr, col, wnorm, dinv, h1b, A2b, 0);
    k_gather_bf<<<GG, blk, 0, stream>>>(rowptr, col, wnorm, dinv, h1b, A2b, 256);
    k_pool_sp<<<NRSU, dim3(64), 0, stream>>>(A2b, seg, SPb, bscale);
    const int NWG2 = ((2 * NRSU + 127) / 128) * 4;  // 64
    k_gemm_mfma<1><<<NWG2, blk, 0, stream>>>(SPb, W2T, out, nullptr, 2 * NRSU, b2, bscale);
}

// Round 18
// 300.449 us; speedup vs baseline: 1.0305x; 1.0305x over previous
//
#include <hip/hip_runtime.h>

#define N_NODES 50000
#define E_EDGES 400000
#define DIM     512
#define NRSU    1000
#define NVEH    (N_NODES - NRSU)
#define NB_SCAN 196           // ceil(50000/256)

typedef __attribute__((ext_vector_type(8))) __bf16 bf16x8;
typedef __attribute__((ext_vector_type(4))) float  f32x4;
typedef __attribute__((ext_vector_type(8))) unsigned short ush8v;
typedef __attribute__((ext_vector_type(4))) unsigned short ush4v;

// ---------- bf16 helpers (RNE) ----------
__device__ __forceinline__ unsigned short f2bf_rne(float x) {
    unsigned u = __float_as_uint(x);
    unsigned r = u + 0x7fff + ((u >> 16) & 1);
    return (unsigned short)(r >> 16);
}
// unpack 8 packed bf16 (uint4) -> 8 floats
__device__ __forceinline__ void cvt8(uint4 v, float* f) {
    f[0] = __uint_as_float(v.x << 16); f[1] = __uint_as_float(v.x & 0xffff0000u);
    f[2] = __uint_as_float(v.y << 16); f[3] = __uint_as_float(v.y & 0xffff0000u);
    f[4] = __uint_as_float(v.z << 16); f[5] = __uint_as_float(v.z & 0xffff0000u);
    f[6] = __uint_as_float(v.w << 16); f[7] = __uint_as_float(v.w & 0xffff0000u);
}
// unpack 4 packed bf16 (uint2) -> 4 floats
__device__ __forceinline__ void cvt4(uint2 v, float* f) {
    f[0] = __uint_as_float(v.x << 16); f[1] = __uint_as_float(v.x & 0xffff0000u);
    f[2] = __uint_as_float(v.y << 16); f[3] = __uint_as_float(v.y & 0xffff0000u);
}

// ---------- async global->LDS (16B per lane) ----------
typedef __attribute__((address_space(1))) const unsigned char ga_u8;
typedef __attribute__((address_space(3))) unsigned char la_u8;
__device__ __forceinline__ void gload16(const void* g, void* l) {
    __builtin_amdgcn_global_load_lds((ga_u8*)g, (la_u8*)l, 16, 0, 0);
}

// ---------------- fused prep: zero(cnt) | segbounds | W^T | x->bf16 ----------------
#define PREP_B0 196
#define PREP_B1 (PREP_B0 + 192)
#define PREP_B2 (PREP_B1 + 2 * DIM)
__global__ __launch_bounds__(256) void k_prep(int* __restrict__ cnt,
                                              const int* __restrict__ batch,
                                              int* __restrict__ seg,
                                              const float* __restrict__ W1,
                                              const float* __restrict__ W2,
                                              unsigned short* __restrict__ W1T,
                                              unsigned short* __restrict__ W2T,
                                              const float* __restrict__ x,
                                              unsigned short* __restrict__ xb) {
    int b = blockIdx.x;
    if (b < PREP_B0) {
        int i = b * 256 + threadIdx.x;
        if (i < N_NODES) cnt[i] = 0;
    } else if (b < PREP_B1) {
        int v = (b - PREP_B0) * 256 + threadIdx.x;
        if (v >= NVEH) return;
        int bb = batch[NRSU + v];
        if (v == 0) {
            for (int s = 0; s <= bb; ++s) seg[s] = 0;
        } else {
            int bp = batch[NRSU + v - 1];
            for (int s = bp + 1; s <= bb; ++s) seg[s] = v;
        }
        if (v == NVEH - 1) {
            for (int s = bb + 1; s <= NRSU; ++s) seg[s] = NVEH;
        }
    } else if (b < PREP_B2) {
        int idx = b - PREP_B1;
        const float* W = (idx >= DIM) ? W2 : W1;
        unsigned short* WT = (idx >= DIM) ? W2T : W1T;
        int n = idx & (DIM - 1);
        for (int k = threadIdx.x; k < DIM; k += 256)
            WT[(size_t)n * DIM + k] = f2bf_rne(W[(size_t)k * DIM + n]);
    } else {
        size_t i = ((size_t)(b - PREP_B2) * 256 + threadIdx.x) * 8;
        float4 a = *reinterpret_cast<const float4*>(x + i);
        float4 c = *reinterpret_cast<const float4*>(x + i + 4);
        ush8v o;
        o[0] = f2bf_rne(a.x); o[1] = f2bf_rne(a.y); o[2] = f2bf_rne(a.z); o[3] = f2bf_rne(a.w);
        o[4] = f2bf_rne(c.x); o[5] = f2bf_rne(c.y); o[6] = f2bf_rne(c.z); o[7] = f2bf_rne(c.w);
        *reinterpret_cast<ush8v*>(xb + i) = o;
    }
}

// ---------------- in-degree count ----------------
__global__ void k_count(const int* __restrict__ dst, int* __restrict__ cnt) {
    int e = blockIdx.x * 256 + threadIdx.x;
    if (e < E_EDGES) atomicAdd(&cnt[dst[e]], 1);
}

// ---------------- block-wise exclusive scan ----------------
__global__ __launch_bounds__(256) void k_scan1(const int* __restrict__ cnt,
                                               int* __restrict__ rowptr,
                                               int* __restrict__ bsum) {
    __shared__ int sh[256];
    int tid = threadIdx.x;
    int i = blockIdx.x * 256 + tid;
    int v = (i < N_NODES) ? cnt[i] : 0;
    sh[tid] = v;
    __syncthreads();
    #pragma unroll
    for (int off = 1; off < 256; off <<= 1) {
        int t = (tid >= off) ? sh[tid - off] : 0;
        __syncthreads();
        sh[tid] += t;
        __syncthreads();
    }
    if (i < N_NODES) rowptr[i] = sh[tid] - v;
    if (tid == 255) bsum[blockIdx.x] = sh[255];
}

__global__ __launch_bounds__(256) void k_scan2(int* __restrict__ bsum) {
    __shared__ int sh[256];
    int tid = threadIdx.x;
    int v = (tid < NB_SCAN) ? bsum[tid] : 0;
    sh[tid] = v;
    __syncthreads();
    #pragma unroll
    for (int off = 1; off < 256; off <<= 1) {
        int t = (tid >= off) ? sh[tid - off] : 0;
        __syncthreads();
        sh[tid] += t;
        __syncthreads();
    }
    if (tid < NB_SCAN) bsum[tid] = sh[tid] - v;
}

// scan finalize + dinv + zero fill counters (merged)
__global__ void k_scan3(int* __restrict__ rowptr, const int* __restrict__ bsum,
                        int* __restrict__ cntfill, float* __restrict__ dinv) {
    int i = blockIdx.x * 256 + threadIdx.x;
    if (i < N_NODES) {
        rowptr[i] += bsum[blockIdx.x];
        int c = cntfill[i];
        dinv[i] = rsqrtf((float)c + 1.0f);   // self-loop
        cntfill[i] = 0;                      // becomes fill counter
    }
    if (i == 0) rowptr[N_NODES] = E_EDGES;
}

// ---------------- CSR fill (+ precomputed edge weights) ----------------
__global__ void k_fill(const int* __restrict__ ei, const int* __restrict__ rowptr,
                       int* __restrict__ fill, int* __restrict__ col,
                       const float* __restrict__ dinv, float* __restrict__ wnorm) {
    int e = blockIdx.x * 256 + threadIdx.x;
    if (e >= E_EDGES) return;
    int s = ei[e];
    int d = ei[E_EDGES + e];
    int p = atomicAdd(&fill[d], 1);
    int idx = rowptr[d] + p;
    col[idx] = s;
    wnorm[idx] = dinv[s] * dinv[d];
}

// ---------------- bf16 MFMA GEMM: double-buffered LDS, prefetch-before-compute --------
// (R16 structure: 2-phase, swizzled, 0 bank conflicts, 32 KB LDS, 5 blocks/CU)
template<int MODE>
__global__ __launch_bounds__(256) void k_gemm_mfma(const unsigned short* __restrict__ Ab,
                                                   const unsigned short* __restrict__ BT,
                                                   float* __restrict__ C,
                                                   unsigned short* __restrict__ Cb, int M,
                                                   const float* __restrict__ bias,
                                                   const float* __restrict__ bscale) {
    const int BM = 128, BN = 128, BK = 32, NT = DIM / BK;
    __shared__ unsigned short sA[2][BM * BK];
    __shared__ unsigned short sB[2][BN * BK];

    int tid = threadIdx.x;
    int wv = tid >> 6;
    int ln = tid & 63;

    int wgid;
    if (MODE == 2) {
        const int q = 195, r = 4;      // nwg = 1564 = 8*195 + 4
        int id = blockIdx.x;
        int xcd = id & 7, idx = id >> 3;
        wgid = (xcd < r ? xcd * (q + 1) : r * (q + 1) + (xcd - r) * q) + idx;
    } else {
        wgid = blockIdx.x;
    }
    int col0 = (wgid & 3) * BN;
    int row0 = (wgid >> 2) * BM;

    int wr = wv >> 1, wc = wv & 1;
    int fr = ln & 15;
    int ks16 = ln >> 4;

    int sidx0 = tid, sidx1 = 256 + tid;
    int r0 = sidx0 >> 2, s0 = sidx0 & 3;
    int r1 = sidx1 >> 2, s1 = sidx1 & 3;
    int c0 = ((s0 ^ ((r0 >> 1) & 3)) << 3);
    int c1 = ((s1 ^ ((r1 >> 1) & 3)) << 3);
    int ar0 = row0 + r0; if (ar0 > M - 1) ar0 = M - 1;
    int ar1 = row0 + r1; if (ar1 > M - 1) ar1 = M - 1;
    const unsigned short* ga0 = Ab + (size_t)ar0 * DIM + c0;
    const unsigned short* ga1 = Ab + (size_t)ar1 * DIM + c1;
    const unsigned short* gb0 = BT + (size_t)(col0 + r0) * DIM + c0;
    const unsigned short* gb1 = BT + (size_t)(col0 + r1) * DIM + c1;
    int lb0 = wv * 1024;
    int lb1 = 4096 + wv * 1024;

    f32x4 zero = {0.f, 0.f, 0.f, 0.f};
    f32x4 acc[4][4];
    #pragma unroll
    for (int m = 0; m < 4; ++m)
        #pragma unroll
        for (int n = 0; n < 4; ++n) acc[m][n] = zero;

    gload16(ga0, (char*)sA[0] + lb0);
    gload16(ga1, (char*)sA[0] + lb1);
    gload16(gb0, (char*)sB[0] + lb0);
    gload16(gb1, (char*)sB[0] + lb1);
    __syncthreads();

    #pragma unroll
    for (int t = 0; t < NT; ++t) {
        int cur = t & 1;
        if (t + 1 < NT) {
            int k0n = (t + 1) * BK;
            gload16(ga0 + k0n, (char*)sA[cur ^ 1] + lb0);
            gload16(ga1 + k0n, (char*)sA[cur ^ 1] + lb1);
            gload16(gb0 + k0n, (char*)sB[cur ^ 1] + lb0);
            gload16(gb1 + k0n, (char*)sB[cur ^ 1] + lb1);
        }
        bf16x8 a[4], b[4];
        #pragma unroll
        for (int m = 0; m < 4; ++m) {
            int r = wr * 64 + m * 16 + fr;
            int e = r * BK + ((ks16 ^ ((r >> 1) & 3)) << 3);
            a[m] = *reinterpret_cast<const bf16x8*>(&sA[cur][e]);
        }
        #pragma unroll
        for (int n = 0; n < 4; ++n) {
            int r = wc * 64 + n * 16 + fr;
            int e = r * BK + ((ks16 ^ ((r >> 1) & 3)) << 3);
            b[n] = *reinterpret_cast<const bf16x8*>(&sB[cur][e]);
        }
        #pragma unroll
        for (int m = 0; m < 4; ++m)
            #pragma unroll
            for (int n = 0; n < 4; ++n)
                acc[m][n] = __builtin_amdgcn_mfma_f32_16x16x32_bf16(a[m], b[n], acc[m][n], 0, 0, 0);
        __syncthreads();
    }

    int rbase = row0 + wr * 64 + (ln >> 4) * 4;
    int cbase = col0 + wc * 64 + (ln & 15);
    #pragma unroll
    for (int m = 0; m < 4; ++m)
        #pragma unroll
        for (int r4 = 0; r4 < 4; ++r4) {
            int row = rbase + m * 16 + r4;
            if (row < M) {
                if (MODE == 2) {
                    #pragma unroll
                    for (int n = 0; n < 4; ++n) {
                        int cc = cbase + n * 16;
                        Cb[(size_t)row * DIM + cc] =
                            f2bf_rne(fmaxf(acc[m][n][r4] + bias[cc], 0.f));
                    }
                } else {
                    float bs = bscale[row];
                    float* dst = (row < NRSU) ? (C + (size_t)row * 1024)
                                              : (C + (size_t)(row - NRSU) * 1024 + 512);
                    #pragma unroll
                    for (int n = 0; n < 4; ++n) {
                        int cc = cbase + n * 16;
                        dst[cc] = acc[m][n][r4] + bias[cc] * bs;
                    }
                }
            }
        }
}

// ---------------- col-split CSR gather on bf16 rows -> bf16 plane ----------------
__global__ __launch_bounds__(256) void k_gather_bf(const int* __restrict__ rowptr,
                                                   const int* __restrict__ col,
                                                   const float* __restrict__ wnorm,
                                                   const float* __restrict__ dinv,
                                                   const unsigned short* __restrict__ pre,
                                                   unsigned short* __restrict__ ob,
                                                   int coff) {
    int node = blockIdx.x * 4 + (threadIdx.x >> 6);
    if (node >= N_NODES) return;
    int lane = threadIdx.x & 63;
    int c = coff + lane * 4;

    float di = dinv[node];
    float w0 = di * di;
    float s[4], t[4];
    {
        uint2 sv = *reinterpret_cast<const uint2*>(pre + (size_t)node * DIM + c);
        float fa[4]; cvt4(sv, fa);
        #pragma unroll
        for (int i = 0; i < 4; ++i) { s[i] = w0 * fa[i]; t[i] = 0.f; }
    }

    int beg = rowptr[node], end = rowptr[node + 1];
    int deg = end - beg;
    for (int j0 = 0; j0 < deg; j0 += 64) {
        int j = j0 + lane;
        int cj = 0; float wj = 0.f;
        if (j < deg) { cj = col[beg + j]; wj = wnorm[beg + j]; }
        int lim = deg - j0; if (lim > 64) lim = 64;
        for (int jj = 0; jj < lim; jj += 8) {
            int sidx[8]; float sw[8];
            #pragma unroll
            for (int q = 0; q < 8; ++q) {
                sidx[q] = __shfl(cj, jj + q);
                sw[q]   = __shfl(wj, jj + q);
            }
            uint2 v[8];
            #pragma unroll
            for (int q = 0; q < 8; ++q)
                v[q] = *reinterpret_cast<const uint2*>(pre + (size_t)sidx[q] * DIM + c);
            #pragma unroll
            for (int q = 0; q < 8; ++q) {
                float f[4]; cvt4(v[q], f);
                if ((q & 1) == 0) {
                    #pragma unroll
                    for (int i = 0; i < 4; ++i) s[i] = fmaf(sw[q], f[i], s[i]);
                } else {
                    #pragma unroll
                    for (int i = 0; i < 4; ++i) t[i] = fmaf(sw[q], f[i], t[i]);
                }
            }
        }
    }
    ush4v h;
    #pragma unroll
    for (int i = 0; i < 4; ++i) h[i] = f2bf_rne(s[i] + t[i]);
    *reinterpret_cast<ush4v*>(ob + (size_t)node * DIM + c) = h;
}

// ---------------- pool from bf16 A2 -> single SPb plane (col-split, grid 2000) --------
__global__ __launch_bounds__(64) void k_pool_sp(const unsigned short* __restrict__ A2b,
                                                const int* __restrict__ seg,
                                                unsigned short* __restrict__ SPb,
                                                float* __restrict__ bscale) {
    int s = blockIdx.x >> 1;            // segment 0..999
    int half = blockIdx.x & 1;          // column half
    int c = half * 256 + threadIdx.x * 4;   // 64 threads x 4 cols = 256 cols

    {
        uint2 v = *reinterpret_cast<const uint2*>(A2b + (size_t)s * DIM + c);
        *reinterpret_cast<uint2*>(SPb + (size_t)s * DIM + c) = v;
    }
    int beg = seg[s], end = seg[s + 1];
    float acc[4] = {0.f, 0.f, 0.f, 0.f};
    for (int v = beg; v < end; ++v) {
        uint2 t = *reinterpret_cast<const uint2*>(A2b + (size_t)(NRSU + v) * DIM + c);
        float f[4]; cvt4(t, f);
        #pragma unroll
        for (int i = 0; i < 4; ++i) acc[i] += f[i];
    }
    float inv = 1.0f / fmaxf((float)(end - beg), 1.0f);
    ush4v h;
    #pragma unroll
    for (int i = 0; i < 4; ++i) h[i] = f2bf_rne(acc[i] * inv);
    *reinterpret_cast<ush4v*>(SPb + (size_t)(NRSU + s) * DIM + c) = h;
    if (threadIdx.x == 0 && half == 0) {
        bscale[s] = 1.0f;
        bscale[NRSU + s] = (end > beg) ? 1.0f : 0.0f;   // empty segment: ref gives exact 0
    }
}

extern "C" void kernel_launch(void* const* d_in, const int* in_sizes, int n_in,
                              void* d_out, int out_size, void* d_ws, size_t ws_size,
                              hipStream_t stream) {
    const float* x     = (const float*)d_in[0];
    const int*   ei    = (const int*)d_in[1];
    const int*   batch = (const int*)d_in[2];
    const float* W1    = (const float*)d_in[3];
    const float* b1    = (const float*)d_in[4];
    const float* W2    = (const float*)d_in[5];
    const float* b2    = (const float*)d_in[6];
    float* out = (float*)d_out;

    char* ws = (char*)d_ws;
    const size_t HALF = (size_t)N_NODES * DIM * 2;
    unsigned short* Axb = (unsigned short*)(ws);
    unsigned short* A2b = (unsigned short*)(ws);
    unsigned short* h1b = (unsigned short*)(ws + 2 * HALF);
    unsigned short* xb  = (unsigned short*)(ws + 3 * HALF);
    char* p = ws + 4 * HALF;
    float* dinv    = (float*)p;                p += (size_t)N_NODES * 4;
    int*   cnt     = (int*)p;                  p += (size_t)N_NODES * 4;
    int*   rowptr  = (int*)p;                  p += (size_t)(N_NODES + 4) * 4;
    int*   col     = (int*)p;                  p += (size_t)E_EDGES * 4;
    float* wnorm   = (float*)p;                p += (size_t)E_EDGES * 4;
    int*   bsum    = (int*)p;                  p += 1024;
    int*   seg     = (int*)p;                  p += (size_t)(NRSU + 8) * 4;
    unsigned short* SPb = (unsigned short*)p;  p += (size_t)2 * NRSU * DIM * 2;
    float* bscale  = (float*)p;                p += (size_t)2 * NRSU * 4;
    unsigned short* W1T = (unsigned short*)p;  p += (size_t)DIM * DIM * 2;
    unsigned short* W2T = (unsigned short*)p;  p += (size_t)DIM * DIM * 2;

    dim3 blk(256);
    const int gN = (N_NODES + 255) / 256;
    const int gE = (E_EDGES + 255) / 256;

    const int PREP_NB = PREP_B2 + (int)((size_t)N_NODES * DIM / 8 / 256);
    k_prep  <<<PREP_NB, blk, 0, stream>>>(cnt, batch, seg, W1, W2, W1T, W2T, x, xb);
    k_count <<<gE, blk, 0, stream>>>(ei + E_EDGES, cnt);
    k_scan1 <<<gN, blk, 0, stream>>>(cnt, rowptr, bsum);
    k_scan2 <<<1,  blk, 0, stream>>>(bsum);
    k_scan3 <<<gN, blk, 0, stream>>>(rowptr, bsum, cnt, dinv);
    k_fill  <<<gE, blk, 0, stream>>>(ei, rowptr, cnt, col, dinv, wnorm);

    const int GG = (N_NODES + 3) / 4;

    // ---- layer 1 ----
    k_gather_bf<<<GG, blk, 0, stream>>>(rowptr, col, wnorm, dinv, xb, Axb, 0);
    k_gather_bf<<<GG, blk, 0, stream>>>(rowptr, col, wnorm, dinv, xb, Axb, 256);
    const int NWG1 = ((N_NODES + 127) / 128) * 4;   // 1564
    k_gemm_mfma<2><<<NWG1, blk, 0, stream>>>(Axb, W1T, nullptr, h1b, N_NODES, b1, nullptr);

    // ---- layer 2 ----
    k_gather_bf<<<GG, blk, 0, stream>>>(rowptr, col, wnorm, dinv, h1b, A2b, 0);
    k_gather_bf<<<GG, blk, 0, stream>>>(rowptr, col, wnorm, dinv, h1b, A2b, 256);
    k_pool_sp<<<2 * NRSU, dim3(64), 0, stream>>>(A2b, seg, SPb, bscale);
    const int NWG2 = ((2 * NRSU + 127) / 128) * 4;  // 64
    k_gemm_mfma<1><<<NWG2, blk, 0, stream>>>(SPb, W2T, out, nullptr, 2 * NRSU, b2, bscale);
}